// Round 2
// baseline (152.743 us; speedup 1.0000x reference)
//
#include <hip/hip_runtime.h>
#include <hip/hip_bf16.h>

// d[e] = || R[idx_i[e]] - R[idx_j[e]] ||
//
// R1 analysis: gather-probe-bound (6 random dword gathers/edge -> 38.4M
// line probes, ~62us at 1 probe/cy/CU). Fix: repack R [N,3] -> R4 [N,4]
// (16B-aligned rows) in d_ws so each atom is ONE dwordx4 gather that never
// splits a cache line: 2 probes/edge instead of 6.
// Streaming idx/out use nontemporal hints to keep the 1.6MB R4 table in L2.

typedef int   v4i __attribute__((ext_vector_type(4)));
typedef float v4f __attribute__((ext_vector_type(4)));

__global__ __launch_bounds__(256) void pad_R_kernel(
    const float* __restrict__ R, float* __restrict__ R4, int n_atoms)
{
    const int i = blockIdx.x * blockDim.x + threadIdx.x;
    if (i < n_atoms) {
        // 3 coalesced-ish reads of a 1.2MB table (L2-resident after warmup).
        const float x = R[3 * i + 0];
        const float y = R[3 * i + 1];
        const float z = R[3 * i + 2];
        v4f v = {x, y, z, 0.0f};
        *(v4f*)(R4 + 4 * (size_t)i) = v;
    }
}

__global__ __launch_bounds__(256) void pairwise_dist_kernel(
    const float* __restrict__ R4,
    const int* __restrict__ idx_i,
    const int* __restrict__ idx_j,
    float* __restrict__ out,
    int n_quads)
{
    const int quad = blockIdx.x * blockDim.x + threadIdx.x;
    if (quad >= n_quads) return;

    // Streaming index loads: nontemporal (don't pollute L2).
    const v4i a = __builtin_nontemporal_load((const v4i*)idx_i + quad);
    const v4i b = __builtin_nontemporal_load((const v4i*)idx_j + quad);

    // 8 independent 16B gathers, all from the L2-resident R4 table.
    const v4f pa0 = *(const v4f*)(R4 + 4 * (size_t)a.x);
    const v4f pb0 = *(const v4f*)(R4 + 4 * (size_t)b.x);
    const v4f pa1 = *(const v4f*)(R4 + 4 * (size_t)a.y);
    const v4f pb1 = *(const v4f*)(R4 + 4 * (size_t)b.y);
    const v4f pa2 = *(const v4f*)(R4 + 4 * (size_t)a.z);
    const v4f pb2 = *(const v4f*)(R4 + 4 * (size_t)b.z);
    const v4f pa3 = *(const v4f*)(R4 + 4 * (size_t)a.w);
    const v4f pb3 = *(const v4f*)(R4 + 4 * (size_t)b.w);

    v4f o;
    {
        const v4f d = pa0 - pb0;
        o.x = sqrtf(d.x * d.x + d.y * d.y + d.z * d.z);
    }
    {
        const v4f d = pa1 - pb1;
        o.y = sqrtf(d.x * d.x + d.y * d.y + d.z * d.z);
    }
    {
        const v4f d = pa2 - pb2;
        o.z = sqrtf(d.x * d.x + d.y * d.y + d.z * d.z);
    }
    {
        const v4f d = pa3 - pb3;
        o.w = sqrtf(d.x * d.x + d.y * d.y + d.z * d.z);
    }
    __builtin_nontemporal_store(o, (v4f*)out + quad);
}

// Tail kernel for n_edges % 4 != 0 (not hit for 6.4M, kept for correctness).
__global__ __launch_bounds__(64) void pairwise_dist_tail_kernel(
    const float* __restrict__ R4,
    const int* __restrict__ idx_i,
    const int* __restrict__ idx_j,
    float* __restrict__ out,
    int start, int n_edges)
{
    const int e = start + blockIdx.x * blockDim.x + threadIdx.x;
    if (e < n_edges) {
        const v4f pa = *(const v4f*)(R4 + 4 * (size_t)idx_i[e]);
        const v4f pb = *(const v4f*)(R4 + 4 * (size_t)idx_j[e]);
        const v4f d = pa - pb;
        out[e] = sqrtf(d.x * d.x + d.y * d.y + d.z * d.z);
    }
}

extern "C" void kernel_launch(void* const* d_in, const int* in_sizes, int n_in,
                              void* d_out, int out_size, void* d_ws, size_t ws_size,
                              hipStream_t stream)
{
    const float* R     = (const float*)d_in[0];
    const int*   idx_i = (const int*)d_in[1];
    const int*   idx_j = (const int*)d_in[2];
    float*       out   = (float*)d_out;

    const int n_atoms = in_sizes[0] / 3;        // 100,000
    const int n_edges = in_sizes[1];            // 6,400,000
    float*    R4      = (float*)d_ws;           // n_atoms * 4 floats = 1.6 MB

    {
        const int block = 256;
        const int grid  = (n_atoms + block - 1) / block;
        pad_R_kernel<<<grid, block, 0, stream>>>(R, R4, n_atoms);
    }

    const int n_quads = n_edges >> 2;
    {
        const int block = 256;
        const int grid  = (n_quads + block - 1) / block;
        pairwise_dist_kernel<<<grid, block, 0, stream>>>(R4, idx_i, idx_j, out, n_quads);
    }

    const int tail_start = n_quads << 2;
    if (tail_start < n_edges) {
        const int tail = n_edges - tail_start;
        pairwise_dist_tail_kernel<<<(tail + 63) / 64, 64, 0, stream>>>(
            R4, idx_i, idx_j, out, tail_start, n_edges);
    }
}